// Round 11
// baseline (128.880 us; speedup 1.0000x reference)
//
#include <hip/hip_runtime.h>
#include <hip/hip_bf16.h>

#define DIM   128
#define BM    64
#define HALF_NODES 25088            // nodes per LDS half
#define HALF_PAIRS (HALF_NODES / 2) // 12544 uints
#define FULL_PAIRS (2 * HALF_PAIRS) // 25088 uints = 100 KB LDS window

typedef short  bf16x8 __attribute__((ext_vector_type(8)));
typedef float  f32x4  __attribute__((ext_vector_type(4)));

__device__ __forceinline__ ushort f2bf(float f) {   // round-to-nearest-even
    uint u = __float_as_uint(f);
    return (ushort)((u + 0x7FFFu + ((u >> 16) & 1u)) >> 16);
}

// ---------------------------------------------------------------------------
// K1: chunked histograms, LDS-only atomics (100 KB window covers all nodes).
// dst-pass LDS atomicAdd return value = within-chunk rank -> rank[e].
// C=128 blocks -> 128 CUs busy (1 block/CU at 100 KB LDS).
// ---------------------------------------------------------------------------
__global__ __launch_bounds__(1024) void hist_kernel(const int* __restrict__ src,
                                                    const int* __restrict__ dst,
                                                    uint* __restrict__ histD,
                                                    uint* __restrict__ histS,
                                                    int* __restrict__ rank,
                                                    int n_edges, int pairs_row,
                                                    int nhalves, int chunk) {
    __shared__ uint h[FULL_PAIRS];
    const int c   = blockIdx.x;
    const int tid = threadIdx.x;
    const int beg = c * chunk;
    const int end = min(beg + chunk, n_edges);
    for (int pass = 0; pass < 2; ++pass) {
        const int* key = pass ? src : dst;
        uint* outb     = pass ? histS : histD;
        for (int hbase = 0; hbase < nhalves; hbase += 2) {
            const int plo    = hbase * HALF_PAIRS;
            const int wpairs = min(FULL_PAIRS, pairs_row - plo);
            const int wnodes = wpairs * 2;
            const int lo     = plo * 2;
            for (int j = tid; j < wpairs; j += 1024) h[j] = 0;
            __syncthreads();
            for (int e = beg + tid; e < end; e += 1024) {
                int r = key[e] - lo;
                if ((unsigned)r < (unsigned)wnodes) {
                    uint old = atomicAdd(&h[r >> 1], 1u << ((r & 1) * 16));
                    if (pass == 0)
                        rank[e] = (r & 1) ? (int)(old >> 16) : (int)(old & 0xFFFFu);
                }
            }
            __syncthreads();
            uint* row = outb + (size_t)c * pairs_row + plo;
            for (int j = tid; j < wpairs; j += 1024) row[j] = h[j];
            __syncthreads();
        }
    }
}

// ---------------------------------------------------------------------------
// K2: per-node exclusive prefix over chunks (in place, D side only) emitting
// deg_in; S side is read-only (totals -> norm_src).  Tail blocks convert
// W -> WT bf16 transposed (folded cvtw: one fewer launch).
// ---------------------------------------------------------------------------
__global__ __launch_bounds__(256) void prefix_kernel(uint* __restrict__ histD,
                                                     const uint* __restrict__ histS,
                                                     int* __restrict__ deg_in,
                                                     float* __restrict__ norm_src,
                                                     const float* __restrict__ W,
                                                     ushort* __restrict__ WT,
                                                     int pairs_row, int n_nodes,
                                                     int nchunk, int nblk_main) {
    if ((int)blockIdx.x >= nblk_main) {
        int idx = ((int)blockIdx.x - nblk_main) * 256 + threadIdx.x;
        if (idx < DIM * DIM) {
            int k = idx >> 7, c = idx & 127;
            WT[c * DIM + k] = f2bf(W[idx]);
        }
        return;
    }
    int id = blockIdx.x * 256 + threadIdx.x;
    bool isS = id >= pairs_row;
    int j = isS ? id - pairs_row : id;
    if (j >= pairs_row) return;
    if (isS) {
        const uint* col = histS + j;
        uint run0 = 0, run1 = 0;
        for (int c = 0; c < nchunk; ++c) {
            uint v = col[(size_t)c * pairs_row];
            run0 += v & 0xFFFFu;
            run1 += v >> 16;
        }
        int n0 = 2 * j, n1 = 2 * j + 1;
        if (n0 < n_nodes) norm_src[n0] = rsqrtf(fmaxf((float)run0, 1.0f));
        if (n1 < n_nodes) norm_src[n1] = rsqrtf(fmaxf((float)run1, 1.0f));
    } else {
        uint* col = histD + j;
        uint run0 = 0, run1 = 0;
        for (int c = 0; c < nchunk; ++c) {
            uint v = col[(size_t)c * pairs_row];
            col[(size_t)c * pairs_row] = run0 | (run1 << 16);
            run0 += v & 0xFFFFu;
            run1 += v >> 16;
        }
        deg_in[2 * j]     = (int)run0;
        deg_in[2 * j + 1] = (int)run1;
    }
}

// ---------------------------------------------------------------------------
// K3: exclusive scan (redundant-prefix, 4 elems/thread, single launch).
// ---------------------------------------------------------------------------
__global__ __launch_bounds__(1024) void scan4_kernel(const int* __restrict__ deg,
                                                     int* __restrict__ offs, int n) {
    __shared__ int w1[16], w2[16];
    const int tid = threadIdx.x, lane = tid & 63, wid = tid >> 6;
    const int base = blockIdx.x * 4096;

    int part = 0;
    for (int i = base ? tid : n; i < base; i += 1024) part += deg[i];
#pragma unroll
    for (int o = 32; o; o >>= 1) part += __shfl_xor(part, o);
    if (lane == 0) w1[wid] = part;
    __syncthreads();
    int prefix = 0;
#pragma unroll
    for (int k = 0; k < 16; ++k) prefix += w1[k];

    int i0 = base + tid * 4;
    int e0 = (i0 + 0 < n) ? deg[i0 + 0] : 0;
    int e1 = (i0 + 1 < n) ? deg[i0 + 1] : 0;
    int e2 = (i0 + 2 < n) ? deg[i0 + 2] : 0;
    int e3 = (i0 + 3 < n) ? deg[i0 + 3] : 0;
    int s  = e0 + e1 + e2 + e3;
    int sc = s;
#pragma unroll
    for (int o = 1; o < 64; o <<= 1) {
        int t = __shfl_up(sc, o);
        if (lane >= o) sc += t;
    }
    if (lane == 63) w2[wid] = sc;
    __syncthreads();
    int wpre = 0;
    for (int k = 0; k < wid; ++k) wpre += w2[k];
    int excl = prefix + wpre + sc - s;
    int o1 = excl + e0, o2 = o1 + e1, o3 = o2 + e2, o4 = o3 + e3;
    if (i0 + 0 < n) offs[i0 + 1] = o1;
    if (i0 + 1 < n) offs[i0 + 2] = o2;
    if (i0 + 2 < n) offs[i0 + 3] = o3;
    if (i0 + 3 < n) offs[i0 + 4] = o4;
    if (base == 0 && tid == 0) offs[0] = 0;
}

// ---------------------------------------------------------------------------
// K4: streaming scatter, no LDS, no atomics.
// ---------------------------------------------------------------------------
__global__ __launch_bounds__(256) void fill_kernel(const int* __restrict__ src,
                                                   const int* __restrict__ dst,
                                                   const int* __restrict__ offs,
                                                   const uint* __restrict__ histD,
                                                   const int* __restrict__ rank,
                                                   int* __restrict__ esrc,
                                                   int n_edges, int pairs_row,
                                                   int chunk) {
    int e = blockIdx.x * 256 + threadIdx.x;
    if (e >= n_edges) return;
    int t = dst[e];
    int c = e / chunk;
    uint pf = histD[(size_t)c * pairs_row + (t >> 1)];
    int pref = (t & 1) ? (int)(pf >> 16) : (int)(pf & 0xFFFFu);
    esrc[offs[t] + pref + rank[e]] = src[e];
}

// ---------------------------------------------------------------------------
// K5: MFMA transform GEMM.  h[r,:] = bf16( norm_src[r] * (x[r,:] @ W) ).
// (unchanged from round 10 — verified)
// ---------------------------------------------------------------------------
__global__ __launch_bounds__(256, 4) void gemmx_kernel(const float* __restrict__ x,
                                                       const ushort* __restrict__ WT,
                                                       const float* __restrict__ norm_src,
                                                       ushort* __restrict__ h,
                                                       int n_nodes) {
    __shared__ ushort WsT[DIM * DIM];   // 32 KB, swizzled [c][k]
    const int tid = threadIdx.x;

    {
        const uint4* wsrc = reinterpret_cast<const uint4*>(WT);
#pragma unroll
        for (int i = 0; i < 8; ++i) {
            int linear = tid + i * 256;           // 0..2047 16B-units
            uint4 v = wsrc[linear];
            int byte = linear * 16;
            int c = byte >> 8;
            int swz = byte ^ ((c & 7) << 4);
            *reinterpret_cast<uint4*>(reinterpret_cast<char*>(WsT) + swz) = v;
        }
    }
    __syncthreads();

    const int lane = tid & 63;
    const int w    = tid >> 6;
    const int r0   = blockIdx.x * BM;
    const int rowm = r0 + w * 16 + (lane & 15);
    const int rowc = min(rowm, n_nodes - 1);
    const float4* X4 = reinterpret_cast<const float4*>(x);

    f32x4 acc[8];
#pragma unroll
    for (int t = 0; t < 8; ++t) acc[t] = (f32x4){0.f, 0.f, 0.f, 0.f};

#pragma unroll
    for (int s = 0; s < 4; ++s) {
        int idx = rowc * 32 + s * 8 + (lane >> 4) * 2;
        float4 v0 = X4[idx];
        float4 v1 = X4[idx + 1];
        bf16x8 a;
        a[0] = (short)f2bf(v0.x); a[1] = (short)f2bf(v0.y);
        a[2] = (short)f2bf(v0.z); a[3] = (short)f2bf(v0.w);
        a[4] = (short)f2bf(v1.x); a[5] = (short)f2bf(v1.y);
        a[6] = (short)f2bf(v1.z); a[7] = (short)f2bf(v1.w);
#pragma unroll
        for (int t = 0; t < 8; ++t) {
            int c   = t * 16 + (lane & 15);
            int ofs = c * 256 + s * 64 + (lane >> 4) * 16;
            ofs ^= (c & 7) << 4;
            bf16x8 b = *reinterpret_cast<const bf16x8*>(
                reinterpret_cast<const char*>(WsT) + ofs);
            acc[t] = __builtin_amdgcn_mfma_f32_16x16x32_bf16(a, b, acc[t], 0, 0, 0);
        }
    }

#pragma unroll
    for (int i = 0; i < 4; ++i) {
        int row = r0 + w * 16 + (lane >> 4) * 4 + i;
        if (row < n_nodes) {
            float ns = norm_src[row];
            ushort* hp = h + (size_t)row * DIM + (lane & 15);
#pragma unroll
            for (int t = 0; t < 8; ++t)
                hp[t * 16] = f2bf(acc[t][i] * ns);
        }
    }
}

// ---------------------------------------------------------------------------
// K6: gather, 2 nodes per wave.  32-lane group per node, uint2 (4 bf16) per
// lane; one wave-load covers 8 edges of TWO nodes (512 B).  x8 unroll with
// 4-way rotated accumulators.  out[t,:] = nd(t) * sum h[src_e,:] + b.
// ---------------------------------------------------------------------------
__global__ __launch_bounds__(256) void gather_kernel(const ushort* __restrict__ h,
                                                     const int* __restrict__ esrc,
                                                     const int* __restrict__ offs,
                                                     const float* __restrict__ bg,
                                                     float* __restrict__ out,
                                                     int n_nodes) {
    const int grp  = threadIdx.x >> 5;            // 8 groups per block
    const int node = blockIdx.x * 8 + grp;
    const int l    = threadIdx.x & 31;
    const bool valid = node < n_nodes;
    int j = 0, end = 0;
    if (valid) { j = offs[node]; end = offs[node + 1]; }
    const int deg = end - j;
    const uint2* hp = reinterpret_cast<const uint2*>(h);

    float a[4][4];
#pragma unroll
    for (int q = 0; q < 4; ++q)
#pragma unroll
        for (int c = 0; c < 4; ++c) a[q][c] = 0.f;

    for (; j + 7 < end; j += 8) {
        int s[8];
#pragma unroll
        for (int q = 0; q < 8; ++q) s[q] = esrc[j + q];       // broadcast loads
        uint2 u[8];
#pragma unroll
        for (int q = 0; q < 8; ++q) u[q] = hp[(size_t)s[q] * 32 + l];
#pragma unroll
        for (int q = 0; q < 8; ++q) {
            a[q & 3][0] += __uint_as_float(u[q].x << 16);
            a[q & 3][1] += __uint_as_float(u[q].x & 0xFFFF0000u);
            a[q & 3][2] += __uint_as_float(u[q].y << 16);
            a[q & 3][3] += __uint_as_float(u[q].y & 0xFFFF0000u);
        }
    }
    for (; j < end; ++j) {
        uint2 u = hp[(size_t)esrc[j] * 32 + l];
        a[0][0] += __uint_as_float(u.x << 16);
        a[0][1] += __uint_as_float(u.x & 0xFFFF0000u);
        a[0][2] += __uint_as_float(u.y << 16);
        a[0][3] += __uint_as_float(u.y & 0xFFFF0000u);
    }

    if (valid) {
        float nd = rsqrtf(fmaxf((float)deg, 1.0f));
        float4 bv = reinterpret_cast<const float4*>(bg)[l];
        float4 r;
        r.x = (a[0][0] + a[1][0] + a[2][0] + a[3][0]) * nd + bv.x;
        r.y = (a[0][1] + a[1][1] + a[2][1] + a[3][1]) * nd + bv.y;
        r.z = (a[0][2] + a[1][2] + a[2][2] + a[3][2]) * nd + bv.z;
        r.w = (a[0][3] + a[1][3] + a[2][3] + a[3][3]) * nd + bv.w;
        reinterpret_cast<float4*>(out)[(size_t)node * 32 + l] = r;
    }
}

extern "C" void kernel_launch(void* const* d_in, const int* in_sizes, int n_in,
                              void* d_out, int out_size, void* d_ws, size_t ws_size,
                              hipStream_t stream) {
    const float* x   = (const float*)d_in[0];
    const int*   src = (const int*)d_in[1];
    const int*   dst = (const int*)d_in[2];
    const float* W   = (const float*)d_in[3];
    const float* b   = (const float*)d_in[4];
    float* out = (float*)d_out;

    const int n_nodes = in_sizes[0] / DIM;
    const int n_edges = in_sizes[1];

    const int nhalves   = (n_nodes + HALF_NODES - 1) / HALF_NODES;
    const int npad      = nhalves * HALF_NODES;
    const int pairs_row = npad / 2;

    auto need = [&](int C) -> size_t {
        return 2ull * n_nodes * DIM + 2ull * DIM * DIM +
               4ull * ((size_t)2 * npad + 1 + n_nodes +
                       2ull * C * pairs_row + 2ull * n_edges);
    };
    int C = 128;
    if (ws_size < need(128)) C = 64;
    if (ws_size < need(64))  C = 32;
    const int chunk = (n_edges + C - 1) / C;   // <= 25000 < 65536: u16-safe

    // ws layout (all fully overwritten -> NO memset needed):
    // [h N*DIM bf16][WT 128*128 bf16][deg_in npad][offs npad+1][norm_src N]
    // [histD C*pairs][histS C*pairs][rank E][esrc E]
    ushort* h        = (ushort*)d_ws;
    ushort* WT       = h + (size_t)n_nodes * DIM;
    int*    deg_in   = (int*)(WT + DIM * DIM);
    int*    offs     = deg_in + npad;
    float*  norm_src = (float*)(offs + npad + 1);
    uint*   histD    = (uint*)(norm_src + n_nodes);
    uint*   histS    = histD + (size_t)C * pairs_row;
    int*    rank     = (int*)(histS + (size_t)C * pairs_row);
    int*    esrc     = rank + n_edges;

    const int egrid    = (n_edges + 255) / 256;
    const int nblkpref = (2 * pairs_row + 255) / 256;

    hist_kernel<<<C, 1024, 0, stream>>>(src, dst, histD, histS, rank,
                                        n_edges, pairs_row, nhalves, chunk);
    prefix_kernel<<<nblkpref + (DIM * DIM + 255) / 256, 256, 0, stream>>>(
        histD, histS, deg_in, norm_src, W, WT, pairs_row, n_nodes, C, nblkpref);
    gemmx_kernel<<<(n_nodes + BM - 1) / BM, 256, 0, stream>>>(
        x, WT, norm_src, h, n_nodes);
    scan4_kernel<<<(npad + 4095) / 4096, 1024, 0, stream>>>(deg_in, offs, npad);
    fill_kernel<<<egrid, 256, 0, stream>>>(src, dst, offs, histD, rank, esrc,
                                           n_edges, pairs_row, chunk);
    gather_kernel<<<(n_nodes + 7) / 8, 256, 0, stream>>>(
        h, esrc, offs, b, out, n_nodes);
}

// Round 12
// 128.345 us; speedup vs baseline: 1.0042x; 1.0042x over previous
//
#include <hip/hip_runtime.h>
#include <hip/hip_bf16.h>

#define DIM   128
#define BM    64
#define HALF_NODES 25088            // nodes per LDS half
#define HALF_PAIRS (HALF_NODES / 2) // 12544 uints
#define FULL_PAIRS (2 * HALF_PAIRS) // 25088 uints = 100 KB LDS window

typedef short  bf16x8 __attribute__((ext_vector_type(8)));
typedef float  f32x4  __attribute__((ext_vector_type(4)));

__device__ __forceinline__ ushort f2bf(float f) {   // round-to-nearest-even
    uint u = __float_as_uint(f);
    return (ushort)((u + 0x7FFFu + ((u >> 16) & 1u)) >> 16);
}

// ---------------------------------------------------------------------------
// K1: chunked histograms, LDS-only atomics (100 KB window covers all nodes).
// dst-pass LDS atomicAdd return value = within-chunk rank -> rank[e].
// C=128 blocks -> 128 CUs busy (1 block/CU at 100 KB LDS).
// ---------------------------------------------------------------------------
__global__ __launch_bounds__(1024) void hist_kernel(const int* __restrict__ src,
                                                    const int* __restrict__ dst,
                                                    uint* __restrict__ histD,
                                                    uint* __restrict__ histS,
                                                    int* __restrict__ rank,
                                                    int n_edges, int pairs_row,
                                                    int nhalves, int chunk) {
    __shared__ uint h[FULL_PAIRS];
    const int c   = blockIdx.x;
    const int tid = threadIdx.x;
    const int beg = c * chunk;
    const int end = min(beg + chunk, n_edges);
    for (int pass = 0; pass < 2; ++pass) {
        const int* key = pass ? src : dst;
        uint* outb     = pass ? histS : histD;
        for (int hbase = 0; hbase < nhalves; hbase += 2) {
            const int plo    = hbase * HALF_PAIRS;
            const int wpairs = min(FULL_PAIRS, pairs_row - plo);
            const int wnodes = wpairs * 2;
            const int lo     = plo * 2;
            for (int j = tid; j < wpairs; j += 1024) h[j] = 0;
            __syncthreads();
            for (int e = beg + tid; e < end; e += 1024) {
                int r = key[e] - lo;
                if ((unsigned)r < (unsigned)wnodes) {
                    uint old = atomicAdd(&h[r >> 1], 1u << ((r & 1) * 16));
                    if (pass == 0)
                        rank[e] = (r & 1) ? (int)(old >> 16) : (int)(old & 0xFFFFu);
                }
            }
            __syncthreads();
            uint* row = outb + (size_t)c * pairs_row + plo;
            for (int j = tid; j < wpairs; j += 1024) row[j] = h[j];
            __syncthreads();
        }
    }
}

// ---------------------------------------------------------------------------
// K2: per-node exclusive prefix over chunks (in place, D side only) emitting
// deg_in; S side is read-only (totals -> norm_src).  Tail blocks convert
// W -> WT bf16 transposed (folded cvtw).
// ---------------------------------------------------------------------------
__global__ __launch_bounds__(256) void prefix_kernel(uint* __restrict__ histD,
                                                     const uint* __restrict__ histS,
                                                     int* __restrict__ deg_in,
                                                     float* __restrict__ norm_src,
                                                     const float* __restrict__ W,
                                                     ushort* __restrict__ WT,
                                                     int pairs_row, int n_nodes,
                                                     int nchunk, int nblk_main) {
    if ((int)blockIdx.x >= nblk_main) {
        int idx = ((int)blockIdx.x - nblk_main) * 256 + threadIdx.x;
        if (idx < DIM * DIM) {
            int k = idx >> 7, c = idx & 127;
            WT[c * DIM + k] = f2bf(W[idx]);
        }
        return;
    }
    int id = blockIdx.x * 256 + threadIdx.x;
    bool isS = id >= pairs_row;
    int j = isS ? id - pairs_row : id;
    if (j >= pairs_row) return;
    if (isS) {
        const uint* col = histS + j;
        uint run0 = 0, run1 = 0;
        for (int c = 0; c < nchunk; ++c) {
            uint v = col[(size_t)c * pairs_row];
            run0 += v & 0xFFFFu;
            run1 += v >> 16;
        }
        int n0 = 2 * j, n1 = 2 * j + 1;
        if (n0 < n_nodes) norm_src[n0] = rsqrtf(fmaxf((float)run0, 1.0f));
        if (n1 < n_nodes) norm_src[n1] = rsqrtf(fmaxf((float)run1, 1.0f));
    } else {
        uint* col = histD + j;
        uint run0 = 0, run1 = 0;
        for (int c = 0; c < nchunk; ++c) {
            uint v = col[(size_t)c * pairs_row];
            col[(size_t)c * pairs_row] = run0 | (run1 << 16);
            run0 += v & 0xFFFFu;
            run1 += v >> 16;
        }
        deg_in[2 * j]     = (int)run0;
        deg_in[2 * j + 1] = (int)run1;
    }
}

// ---------------------------------------------------------------------------
// K3: exclusive scan (redundant-prefix, 4 elems/thread, single launch).
// ---------------------------------------------------------------------------
__global__ __launch_bounds__(1024) void scan4_kernel(const int* __restrict__ deg,
                                                     int* __restrict__ offs, int n) {
    __shared__ int w1[16], w2[16];
    const int tid = threadIdx.x, lane = tid & 63, wid = tid >> 6;
    const int base = blockIdx.x * 4096;

    int part = 0;
    for (int i = base ? tid : n; i < base; i += 1024) part += deg[i];
#pragma unroll
    for (int o = 32; o; o >>= 1) part += __shfl_xor(part, o);
    if (lane == 0) w1[wid] = part;
    __syncthreads();
    int prefix = 0;
#pragma unroll
    for (int k = 0; k < 16; ++k) prefix += w1[k];

    int i0 = base + tid * 4;
    int e0 = (i0 + 0 < n) ? deg[i0 + 0] : 0;
    int e1 = (i0 + 1 < n) ? deg[i0 + 1] : 0;
    int e2 = (i0 + 2 < n) ? deg[i0 + 2] : 0;
    int e3 = (i0 + 3 < n) ? deg[i0 + 3] : 0;
    int s  = e0 + e1 + e2 + e3;
    int sc = s;
#pragma unroll
    for (int o = 1; o < 64; o <<= 1) {
        int t = __shfl_up(sc, o);
        if (lane >= o) sc += t;
    }
    if (lane == 63) w2[wid] = sc;
    __syncthreads();
    int wpre = 0;
    for (int k = 0; k < wid; ++k) wpre += w2[k];
    int excl = prefix + wpre + sc - s;
    int o1 = excl + e0, o2 = o1 + e1, o3 = o2 + e2, o4 = o3 + e3;
    if (i0 + 0 < n) offs[i0 + 1] = o1;
    if (i0 + 1 < n) offs[i0 + 2] = o2;
    if (i0 + 2 < n) offs[i0 + 3] = o3;
    if (i0 + 3 < n) offs[i0 + 4] = o4;
    if (base == 0 && tid == 0) offs[0] = 0;
}

// ---------------------------------------------------------------------------
// K4: streaming scatter, no LDS, no atomics.
// ---------------------------------------------------------------------------
__global__ __launch_bounds__(256) void fill_kernel(const int* __restrict__ src,
                                                   const int* __restrict__ dst,
                                                   const int* __restrict__ offs,
                                                   const uint* __restrict__ histD,
                                                   const int* __restrict__ rank,
                                                   int* __restrict__ esrc,
                                                   int n_edges, int pairs_row,
                                                   int chunk) {
    int e = blockIdx.x * 256 + threadIdx.x;
    if (e >= n_edges) return;
    int t = dst[e];
    int c = e / chunk;
    uint pf = histD[(size_t)c * pairs_row + (t >> 1)];
    int pref = (t & 1) ? (int)(pf >> 16) : (int)(pf & 0xFFFFu);
    esrc[offs[t] + pref + rank[e]] = src[e];
}

// ---------------------------------------------------------------------------
// K5: MFMA transform GEMM.  h[r,:] = bf16( norm_src[r] * (x[r,:] @ W) ).
// (unchanged — verified r10/r11)
// ---------------------------------------------------------------------------
__global__ __launch_bounds__(256, 4) void gemmx_kernel(const float* __restrict__ x,
                                                       const ushort* __restrict__ WT,
                                                       const float* __restrict__ norm_src,
                                                       ushort* __restrict__ h,
                                                       int n_nodes) {
    __shared__ ushort WsT[DIM * DIM];   // 32 KB, swizzled [c][k]
    const int tid = threadIdx.x;

    {
        const uint4* wsrc = reinterpret_cast<const uint4*>(WT);
#pragma unroll
        for (int i = 0; i < 8; ++i) {
            int linear = tid + i * 256;           // 0..2047 16B-units
            uint4 v = wsrc[linear];
            int byte = linear * 16;
            int c = byte >> 8;
            int swz = byte ^ ((c & 7) << 4);
            *reinterpret_cast<uint4*>(reinterpret_cast<char*>(WsT) + swz) = v;
        }
    }
    __syncthreads();

    const int lane = tid & 63;
    const int w    = tid >> 6;
    const int r0   = blockIdx.x * BM;
    const int rowm = r0 + w * 16 + (lane & 15);
    const int rowc = min(rowm, n_nodes - 1);
    const float4* X4 = reinterpret_cast<const float4*>(x);

    f32x4 acc[8];
#pragma unroll
    for (int t = 0; t < 8; ++t) acc[t] = (f32x4){0.f, 0.f, 0.f, 0.f};

#pragma unroll
    for (int s = 0; s < 4; ++s) {
        int idx = rowc * 32 + s * 8 + (lane >> 4) * 2;
        float4 v0 = X4[idx];
        float4 v1 = X4[idx + 1];
        bf16x8 a;
        a[0] = (short)f2bf(v0.x); a[1] = (short)f2bf(v0.y);
        a[2] = (short)f2bf(v0.z); a[3] = (short)f2bf(v0.w);
        a[4] = (short)f2bf(v1.x); a[5] = (short)f2bf(v1.y);
        a[6] = (short)f2bf(v1.z); a[7] = (short)f2bf(v1.w);
#pragma unroll
        for (int t = 0; t < 8; ++t) {
            int c   = t * 16 + (lane & 15);
            int ofs = c * 256 + s * 64 + (lane >> 4) * 16;
            ofs ^= (c & 7) << 4;
            bf16x8 b = *reinterpret_cast<const bf16x8*>(
                reinterpret_cast<const char*>(WsT) + ofs);
            acc[t] = __builtin_amdgcn_mfma_f32_16x16x32_bf16(a, b, acc[t], 0, 0, 0);
        }
    }

#pragma unroll
    for (int i = 0; i < 4; ++i) {
        int row = r0 + w * 16 + (lane >> 4) * 4 + i;
        if (row < n_nodes) {
            float ns = norm_src[row];
            ushort* hp = h + (size_t)row * DIM + (lane & 15);
#pragma unroll
            for (int t = 0; t < 8; ++t)
                hp[t * 16] = f2bf(acc[t][i] * ns);
        }
    }
}

// ---------------------------------------------------------------------------
// K6: gather (round-10 proven form).  One wave per node, 1 uint (2 bf16) per
// lane, x8 unroll: 8 independent loads in flight against L2/L3 latency.
// out[t,:] = nd(t) * sum h[src_e,:] + b.
// ---------------------------------------------------------------------------
__global__ __launch_bounds__(256) void gather_kernel(const ushort* __restrict__ h,
                                                     const int* __restrict__ esrc,
                                                     const int* __restrict__ offs,
                                                     const float* __restrict__ bg,
                                                     float* __restrict__ out,
                                                     int n_nodes) {
    int node = blockIdx.x * 4 + (threadIdx.x >> 6);
    if (node >= n_nodes) return;
    int lane = threadIdx.x & 63;
    int j = offs[node], end = offs[node + 1];
    int deg = end - j;
    const uint* hp = reinterpret_cast<const uint*>(h);
    float ax[8], ay[8];
#pragma unroll
    for (int q = 0; q < 8; ++q) { ax[q] = 0.f; ay[q] = 0.f; }
    for (; j + 7 < end; j += 8) {
        int   si[8];
        uint  u[8];
#pragma unroll
        for (int q = 0; q < 8; ++q) si[q] = esrc[j + q];
#pragma unroll
        for (int q = 0; q < 8; ++q) u[q] = hp[(size_t)si[q] * 64 + lane];
#pragma unroll
        for (int q = 0; q < 8; ++q) {
            ax[q] += __uint_as_float(u[q] << 16);
            ay[q] += __uint_as_float(u[q] & 0xFFFF0000u);
        }
    }
    for (; j + 3 < end; j += 4) {
        int  si[4];
        uint u[4];
#pragma unroll
        for (int q = 0; q < 4; ++q) si[q] = esrc[j + q];
#pragma unroll
        for (int q = 0; q < 4; ++q) u[q] = hp[(size_t)si[q] * 64 + lane];
#pragma unroll
        for (int q = 0; q < 4; ++q) {
            ax[q] += __uint_as_float(u[q] << 16);
            ay[q] += __uint_as_float(u[q] & 0xFFFF0000u);
        }
    }
    for (; j < end; ++j) {
        uint u = hp[(size_t)esrc[j] * 64 + lane];
        ax[0] += __uint_as_float(u << 16);
        ay[0] += __uint_as_float(u & 0xFFFF0000u);
    }
    float sx = ((ax[0] + ax[1]) + (ax[2] + ax[3])) + ((ax[4] + ax[5]) + (ax[6] + ax[7]));
    float sy = ((ay[0] + ay[1]) + (ay[2] + ay[3])) + ((ay[4] + ay[5]) + (ay[6] + ay[7]));
    float nd = rsqrtf(fmaxf((float)deg, 1.0f));
    float2 bv = reinterpret_cast<const float2*>(bg)[lane];
    float2 r;
    r.x = sx * nd + bv.x;
    r.y = sy * nd + bv.y;
    reinterpret_cast<float2*>(out)[(size_t)node * 64 + lane] = r;
}

extern "C" void kernel_launch(void* const* d_in, const int* in_sizes, int n_in,
                              void* d_out, int out_size, void* d_ws, size_t ws_size,
                              hipStream_t stream) {
    const float* x   = (const float*)d_in[0];
    const int*   src = (const int*)d_in[1];
    const int*   dst = (const int*)d_in[2];
    const float* W   = (const float*)d_in[3];
    const float* b   = (const float*)d_in[4];
    float* out = (float*)d_out;

    const int n_nodes = in_sizes[0] / DIM;
    const int n_edges = in_sizes[1];

    const int nhalves   = (n_nodes + HALF_NODES - 1) / HALF_NODES;
    const int npad      = nhalves * HALF_NODES;
    const int pairs_row = npad / 2;

    auto need = [&](int C) -> size_t {
        return 2ull * n_nodes * DIM + 2ull * DIM * DIM +
               4ull * ((size_t)2 * npad + 1 + n_nodes +
                       2ull * C * pairs_row + 2ull * n_edges);
    };
    int C = 128;
    if (ws_size < need(128)) C = 64;
    if (ws_size < need(64))  C = 32;
    const int chunk = (n_edges + C - 1) / C;   // <= 25000 < 65536: u16-safe

    // ws layout (all fully overwritten -> NO memset needed):
    // [h N*DIM bf16][WT 128*128 bf16][deg_in npad][offs npad+1][norm_src N]
    // [histD C*pairs][histS C*pairs][rank E][esrc E]
    ushort* h        = (ushort*)d_ws;
    ushort* WT       = h + (size_t)n_nodes * DIM;
    int*    deg_in   = (int*)(WT + DIM * DIM);
    int*    offs     = deg_in + npad;
    float*  norm_src = (float*)(offs + npad + 1);
    uint*   histD    = (uint*)(norm_src + n_nodes);
    uint*   histS    = histD + (size_t)C * pairs_row;
    int*    rank     = (int*)(histS + (size_t)C * pairs_row);
    int*    esrc     = rank + n_edges;

    const int egrid    = (n_edges + 255) / 256;
    const int nblkpref = (2 * pairs_row + 255) / 256;

    hist_kernel<<<C, 1024, 0, stream>>>(src, dst, histD, histS, rank,
                                        n_edges, pairs_row, nhalves, chunk);
    prefix_kernel<<<nblkpref + (DIM * DIM + 255) / 256, 256, 0, stream>>>(
        histD, histS, deg_in, norm_src, W, WT, pairs_row, n_nodes, C, nblkpref);
    gemmx_kernel<<<(n_nodes + BM - 1) / BM, 256, 0, stream>>>(
        x, WT, norm_src, h, n_nodes);
    scan4_kernel<<<(npad + 4095) / 4096, 1024, 0, stream>>>(deg_in, offs, npad);
    fill_kernel<<<egrid, 256, 0, stream>>>(src, dst, offs, histD, rank, esrc,
                                           n_edges, pairs_row, chunk);
    gather_kernel<<<(n_nodes + 3) / 4, 256, 0, stream>>>(
        h, esrc, offs, b, out, n_nodes);
}

// Round 13
// 106.818 us; speedup vs baseline: 1.2065x; 1.2015x over previous
//
#include <hip/hip_runtime.h>
#include <hip/hip_bf16.h>

#define DIM   128
#define BM    64
#define HALF_NODES 25088            // nodes per LDS half
#define HALF_PAIRS (HALF_NODES / 2) // 12544 uints
#define FULL_PAIRS (2 * HALF_PAIRS) // 25088 uints = 100 KB LDS window

typedef short  bf16x8 __attribute__((ext_vector_type(8)));
typedef float  f32x4  __attribute__((ext_vector_type(4)));

__device__ __forceinline__ ushort f2bf(float f) {   // round-to-nearest-even
    uint u = __float_as_uint(f);
    return (ushort)((u + 0x7FFFu + ((u >> 16) & 1u)) >> 16);
}

// ---------------------------------------------------------------------------
// K1: chunked histograms, LDS-only atomics, ONE PASS PER BLOCK.
// Grid = 2C: blocks 0..C-1 do the dst pass (histD + rank via the LDS
// atomicAdd return value); blocks C..2C-1 do the src pass (histS).
// Same total dump traffic as the r10 two-pass form, but the per-block
// critical path halves and 128 CUs run concurrently instead of 64.
// ---------------------------------------------------------------------------
__global__ __launch_bounds__(1024) void hist_kernel(const int* __restrict__ src,
                                                    const int* __restrict__ dst,
                                                    uint* __restrict__ histD,
                                                    uint* __restrict__ histS,
                                                    int* __restrict__ rank,
                                                    int n_edges, int pairs_row,
                                                    int nhalves, int chunk,
                                                    int nblkD) {
    __shared__ uint h[FULL_PAIRS];
    const int  tid  = threadIdx.x;
    const bool isD  = (int)blockIdx.x < nblkD;
    const int  c    = isD ? (int)blockIdx.x : (int)blockIdx.x - nblkD;
    const int  beg  = c * chunk;
    const int  end  = min(beg + chunk, n_edges);
    const int* key  = isD ? dst : src;
    uint*      outb = isD ? histD : histS;

    for (int hbase = 0; hbase < nhalves; hbase += 2) {
        const int plo    = hbase * HALF_PAIRS;
        const int wpairs = min(FULL_PAIRS, pairs_row - plo);
        const int wnodes = wpairs * 2;
        const int lo     = plo * 2;
        for (int j = tid; j < wpairs; j += 1024) h[j] = 0;
        __syncthreads();
        for (int e = beg + tid; e < end; e += 1024) {
            int r = key[e] - lo;
            if ((unsigned)r < (unsigned)wnodes) {
                uint old = atomicAdd(&h[r >> 1], 1u << ((r & 1) * 16));
                if (isD)
                    rank[e] = (r & 1) ? (int)(old >> 16) : (int)(old & 0xFFFFu);
            }
        }
        __syncthreads();
        uint* row = outb + (size_t)c * pairs_row + plo;
        for (int j = tid; j < wpairs; j += 1024) row[j] = h[j];
        __syncthreads();
    }
}

// ---------------------------------------------------------------------------
// K2: per-node exclusive prefix over chunks (in place, D side only) emitting
// deg_in; S side read-only (totals -> norm_src).  Tail blocks convert
// W -> WT bf16 transposed (folded cvtw).
// ---------------------------------------------------------------------------
__global__ __launch_bounds__(256) void prefix_kernel(uint* __restrict__ histD,
                                                     const uint* __restrict__ histS,
                                                     int* __restrict__ deg_in,
                                                     float* __restrict__ norm_src,
                                                     const float* __restrict__ W,
                                                     ushort* __restrict__ WT,
                                                     int pairs_row, int n_nodes,
                                                     int nchunk, int nblk_main) {
    if ((int)blockIdx.x >= nblk_main) {
        int idx = ((int)blockIdx.x - nblk_main) * 256 + threadIdx.x;
        if (idx < DIM * DIM) {
            int k = idx >> 7, c = idx & 127;
            WT[c * DIM + k] = f2bf(W[idx]);
        }
        return;
    }
    int id = blockIdx.x * 256 + threadIdx.x;
    bool isS = id >= pairs_row;
    int j = isS ? id - pairs_row : id;
    if (j >= pairs_row) return;
    if (isS) {
        const uint* col = histS + j;
        uint run0 = 0, run1 = 0;
        for (int c = 0; c < nchunk; ++c) {
            uint v = col[(size_t)c * pairs_row];
            run0 += v & 0xFFFFu;
            run1 += v >> 16;
        }
        int n0 = 2 * j, n1 = 2 * j + 1;
        if (n0 < n_nodes) norm_src[n0] = rsqrtf(fmaxf((float)run0, 1.0f));
        if (n1 < n_nodes) norm_src[n1] = rsqrtf(fmaxf((float)run1, 1.0f));
    } else {
        uint* col = histD + j;
        uint run0 = 0, run1 = 0;
        for (int c = 0; c < nchunk; ++c) {
            uint v = col[(size_t)c * pairs_row];
            col[(size_t)c * pairs_row] = run0 | (run1 << 16);
            run0 += v & 0xFFFFu;
            run1 += v >> 16;
        }
        deg_in[2 * j]     = (int)run0;
        deg_in[2 * j + 1] = (int)run1;
    }
}

// ---------------------------------------------------------------------------
// K3: exclusive scan (redundant-prefix, 4 elems/thread, single launch).
// ---------------------------------------------------------------------------
__global__ __launch_bounds__(1024) void scan4_kernel(const int* __restrict__ deg,
                                                     int* __restrict__ offs, int n) {
    __shared__ int w1[16], w2[16];
    const int tid = threadIdx.x, lane = tid & 63, wid = tid >> 6;
    const int base = blockIdx.x * 4096;

    int part = 0;
    for (int i = base ? tid : n; i < base; i += 1024) part += deg[i];
#pragma unroll
    for (int o = 32; o; o >>= 1) part += __shfl_xor(part, o);
    if (lane == 0) w1[wid] = part;
    __syncthreads();
    int prefix = 0;
#pragma unroll
    for (int k = 0; k < 16; ++k) prefix += w1[k];

    int i0 = base + tid * 4;
    int e0 = (i0 + 0 < n) ? deg[i0 + 0] : 0;
    int e1 = (i0 + 1 < n) ? deg[i0 + 1] : 0;
    int e2 = (i0 + 2 < n) ? deg[i0 + 2] : 0;
    int e3 = (i0 + 3 < n) ? deg[i0 + 3] : 0;
    int s  = e0 + e1 + e2 + e3;
    int sc = s;
#pragma unroll
    for (int o = 1; o < 64; o <<= 1) {
        int t = __shfl_up(sc, o);
        if (lane >= o) sc += t;
    }
    if (lane == 63) w2[wid] = sc;
    __syncthreads();
    int wpre = 0;
    for (int k = 0; k < wid; ++k) wpre += w2[k];
    int excl = prefix + wpre + sc - s;
    int o1 = excl + e0, o2 = o1 + e1, o3 = o2 + e2, o4 = o3 + e3;
    if (i0 + 0 < n) offs[i0 + 1] = o1;
    if (i0 + 1 < n) offs[i0 + 2] = o2;
    if (i0 + 2 < n) offs[i0 + 3] = o3;
    if (i0 + 3 < n) offs[i0 + 4] = o4;
    if (base == 0 && tid == 0) offs[0] = 0;
}

// ---------------------------------------------------------------------------
// K4: streaming scatter, no LDS, no atomics.
// ---------------------------------------------------------------------------
__global__ __launch_bounds__(256) void fill_kernel(const int* __restrict__ src,
                                                   const int* __restrict__ dst,
                                                   const int* __restrict__ offs,
                                                   const uint* __restrict__ histD,
                                                   const int* __restrict__ rank,
                                                   int* __restrict__ esrc,
                                                   int n_edges, int pairs_row,
                                                   int chunk) {
    int e = blockIdx.x * 256 + threadIdx.x;
    if (e >= n_edges) return;
    int t = dst[e];
    int c = e / chunk;
    uint pf = histD[(size_t)c * pairs_row + (t >> 1)];
    int pref = (t & 1) ? (int)(pf >> 16) : (int)(pf & 0xFFFFu);
    esrc[offs[t] + pref + rank[e]] = src[e];
}

// ---------------------------------------------------------------------------
// K5: MFMA transform GEMM.  h[r,:] = bf16( norm_src[r] * (x[r,:] @ W) ).
// (unchanged — verified r10-r12)
// ---------------------------------------------------------------------------
__global__ __launch_bounds__(256, 4) void gemmx_kernel(const float* __restrict__ x,
                                                       const ushort* __restrict__ WT,
                                                       const float* __restrict__ norm_src,
                                                       ushort* __restrict__ h,
                                                       int n_nodes) {
    __shared__ ushort WsT[DIM * DIM];   // 32 KB, swizzled [c][k]
    const int tid = threadIdx.x;

    {
        const uint4* wsrc = reinterpret_cast<const uint4*>(WT);
#pragma unroll
        for (int i = 0; i < 8; ++i) {
            int linear = tid + i * 256;           // 0..2047 16B-units
            uint4 v = wsrc[linear];
            int byte = linear * 16;
            int c = byte >> 8;
            int swz = byte ^ ((c & 7) << 4);
            *reinterpret_cast<uint4*>(reinterpret_cast<char*>(WsT) + swz) = v;
        }
    }
    __syncthreads();

    const int lane = tid & 63;
    const int w    = tid >> 6;
    const int r0   = blockIdx.x * BM;
    const int rowm = r0 + w * 16 + (lane & 15);
    const int rowc = min(rowm, n_nodes - 1);
    const float4* X4 = reinterpret_cast<const float4*>(x);

    f32x4 acc[8];
#pragma unroll
    for (int t = 0; t < 8; ++t) acc[t] = (f32x4){0.f, 0.f, 0.f, 0.f};

#pragma unroll
    for (int s = 0; s < 4; ++s) {
        int idx = rowc * 32 + s * 8 + (lane >> 4) * 2;
        float4 v0 = X4[idx];
        float4 v1 = X4[idx + 1];
        bf16x8 a;
        a[0] = (short)f2bf(v0.x); a[1] = (short)f2bf(v0.y);
        a[2] = (short)f2bf(v0.z); a[3] = (short)f2bf(v0.w);
        a[4] = (short)f2bf(v1.x); a[5] = (short)f2bf(v1.y);
        a[6] = (short)f2bf(v1.z); a[7] = (short)f2bf(v1.w);
#pragma unroll
        for (int t = 0; t < 8; ++t) {
            int c   = t * 16 + (lane & 15);
            int ofs = c * 256 + s * 64 + (lane >> 4) * 16;
            ofs ^= (c & 7) << 4;
            bf16x8 b = *reinterpret_cast<const bf16x8*>(
                reinterpret_cast<const char*>(WsT) + ofs);
            acc[t] = __builtin_amdgcn_mfma_f32_16x16x32_bf16(a, b, acc[t], 0, 0, 0);
        }
    }

#pragma unroll
    for (int i = 0; i < 4; ++i) {
        int row = r0 + w * 16 + (lane >> 4) * 4 + i;
        if (row < n_nodes) {
            float ns = norm_src[row];
            ushort* hp = h + (size_t)row * DIM + (lane & 15);
#pragma unroll
            for (int t = 0; t < 8; ++t)
                hp[t * 16] = f2bf(acc[t][i] * ns);
        }
    }
}

// ---------------------------------------------------------------------------
// K6: gather (r10 proven form).  One wave per node, 1 uint (2 bf16) per lane,
// x8 unroll.  out[t,:] = nd(t) * sum h[src_e,:] + b.
// ---------------------------------------------------------------------------
__global__ __launch_bounds__(256) void gather_kernel(const ushort* __restrict__ h,
                                                     const int* __restrict__ esrc,
                                                     const int* __restrict__ offs,
                                                     const float* __restrict__ bg,
                                                     float* __restrict__ out,
                                                     int n_nodes) {
    int node = blockIdx.x * 4 + (threadIdx.x >> 6);
    if (node >= n_nodes) return;
    int lane = threadIdx.x & 63;
    int j = offs[node], end = offs[node + 1];
    int deg = end - j;
    const uint* hp = reinterpret_cast<const uint*>(h);
    float ax[8], ay[8];
#pragma unroll
    for (int q = 0; q < 8; ++q) { ax[q] = 0.f; ay[q] = 0.f; }
    for (; j + 7 < end; j += 8) {
        int   si[8];
        uint  u[8];
#pragma unroll
        for (int q = 0; q < 8; ++q) si[q] = esrc[j + q];
#pragma unroll
        for (int q = 0; q < 8; ++q) u[q] = hp[(size_t)si[q] * 64 + lane];
#pragma unroll
        for (int q = 0; q < 8; ++q) {
            ax[q] += __uint_as_float(u[q] << 16);
            ay[q] += __uint_as_float(u[q] & 0xFFFF0000u);
        }
    }
    for (; j + 3 < end; j += 4) {
        int  si[4];
        uint u[4];
#pragma unroll
        for (int q = 0; q < 4; ++q) si[q] = esrc[j + q];
#pragma unroll
        for (int q = 0; q < 4; ++q) u[q] = hp[(size_t)si[q] * 64 + lane];
#pragma unroll
        for (int q = 0; q < 4; ++q) {
            ax[q] += __uint_as_float(u[q] << 16);
            ay[q] += __uint_as_float(u[q] & 0xFFFF0000u);
        }
    }
    for (; j < end; ++j) {
        uint u = hp[(size_t)esrc[j] * 64 + lane];
        ax[0] += __uint_as_float(u << 16);
        ay[0] += __uint_as_float(u & 0xFFFF0000u);
    }
    float sx = ((ax[0] + ax[1]) + (ax[2] + ax[3])) + ((ax[4] + ax[5]) + (ax[6] + ax[7]));
    float sy = ((ay[0] + ay[1]) + (ay[2] + ay[3])) + ((ay[4] + ay[5]) + (ay[6] + ay[7]));
    float nd = rsqrtf(fmaxf((float)deg, 1.0f));
    float2 bv = reinterpret_cast<const float2*>(bg)[lane];
    float2 r;
    r.x = sx * nd + bv.x;
    r.y = sy * nd + bv.y;
    reinterpret_cast<float2*>(out)[(size_t)node * 64 + lane] = r;
}

extern "C" void kernel_launch(void* const* d_in, const int* in_sizes, int n_in,
                              void* d_out, int out_size, void* d_ws, size_t ws_size,
                              hipStream_t stream) {
    const float* x   = (const float*)d_in[0];
    const int*   src = (const int*)d_in[1];
    const int*   dst = (const int*)d_in[2];
    const float* W   = (const float*)d_in[3];
    const float* b   = (const float*)d_in[4];
    float* out = (float*)d_out;

    const int n_nodes = in_sizes[0] / DIM;
    const int n_edges = in_sizes[1];

    const int nhalves   = (n_nodes + HALF_NODES - 1) / HALF_NODES;
    const int npad      = nhalves * HALF_NODES;
    const int pairs_row = npad / 2;

    auto need = [&](int C) -> size_t {
        return 2ull * n_nodes * DIM + 2ull * DIM * DIM +
               4ull * ((size_t)2 * npad + 1 + n_nodes +
                       2ull * C * pairs_row + 2ull * n_edges);
    };
    int C = 64;                              // per pass (D and S)
    if (ws_size < need(64)) C = 32;
    if (ws_size < need(32)) C = 16;
    const int chunk = (n_edges + C - 1) / C; // <= 50000 < 65536: u16-safe

    // ws layout (all fully overwritten -> NO memset needed):
    // [h N*DIM bf16][WT 128*128 bf16][deg_in npad][offs npad+1][norm_src N]
    // [histD C*pairs][histS C*pairs][rank E][esrc E]
    ushort* h        = (ushort*)d_ws;
    ushort* WT       = h + (size_t)n_nodes * DIM;
    int*    deg_in   = (int*)(WT + DIM * DIM);
    int*    offs     = deg_in + npad;
    float*  norm_src = (float*)(offs + npad + 1);
    uint*   histD    = (uint*)(norm_src + n_nodes);
    uint*   histS    = histD + (size_t)C * pairs_row;
    int*    rank     = (int*)(histS + (size_t)C * pairs_row);
    int*    esrc     = rank + n_edges;

    const int egrid    = (n_edges + 255) / 256;
    const int nblkpref = (2 * pairs_row + 255) / 256;

    hist_kernel<<<2 * C, 1024, 0, stream>>>(src, dst, histD, histS, rank,
                                            n_edges, pairs_row, nhalves, chunk, C);
    prefix_kernel<<<nblkpref + (DIM * DIM + 255) / 256, 256, 0, stream>>>(
        histD, histS, deg_in, norm_src, W, WT, pairs_row, n_nodes, C, nblkpref);
    gemmx_kernel<<<(n_nodes + BM - 1) / BM, 256, 0, stream>>>(
        x, WT, norm_src, h, n_nodes);
    scan4_kernel<<<(npad + 4095) / 4096, 1024, 0, stream>>>(deg_in, offs, npad);
    fill_kernel<<<egrid, 256, 0, stream>>>(src, dst, offs, histD, rank, esrc,
                                           n_edges, pairs_row, chunk);
    gather_kernel<<<(n_nodes + 3) / 4, 256, 0, stream>>>(
        h, esrc, offs, b, out, n_nodes);
}